// Round 20
// baseline (2607.362 us; speedup 1.0000x reference)
//
#include <hip/hip_runtime.h>
#include <hip/hip_bf16.h>
#include <math.h>

// ---------------- problem constants ----------------
#define NTOK 401408              // 8*1024*49 tokens
#define NWIN 8192                // 8*1024 windows
#define NCHUNK 4
#define TOK_PER_CHUNK (NTOK / NCHUNK)   // 100352
#define WIN_PER_CHUNK (NWIN / NCHUNK)   // 2048

typedef __attribute__((ext_vector_type(8))) short bf16x8_t;
typedef __attribute__((ext_vector_type(4))) float f32x4_t;

__device__ __forceinline__ float bf2f(unsigned int u) {
    return __uint_as_float(u << 16);
}
__device__ __forceinline__ unsigned short f2bf(float f) {
    unsigned int x = __float_as_uint(f);
    x += 0x7fffu + ((x >> 16) & 1u);   // RNE
    return (unsigned short)(x >> 16);
}
__device__ __forceinline__ unsigned int pack2bf(float a, float b) {
    return (unsigned int)f2bf(a) | ((unsigned int)f2bf(b) << 16);
}

// direct global->LDS, 16B/lane; LDS dest = wave-uniform base + lane*16 (HW rule)
#define GLOAD16(gsrc, ldst)                                                        \
    __builtin_amdgcn_global_load_lds(                                              \
        (const __attribute__((address_space(1))) unsigned int*)(gsrc),             \
        (__attribute__((address_space(3))) unsigned int*)(ldst), 16, 0, 0)

// ---------------- all weight transposes in one dispatch:  WT[n][k] = W[k][n] ------
__global__ void wt_all_kernel(const float* __restrict__ s0, const float* __restrict__ s1,
                              const float* __restrict__ s2, const float* __restrict__ s3,
                              const float* __restrict__ s4, const float* __restrict__ s5,
                              unsigned short* __restrict__ d0, unsigned short* __restrict__ d1,
                              unsigned short* __restrict__ d2, unsigned short* __restrict__ d3,
                              unsigned short* __restrict__ d4, unsigned short* __restrict__ d5) {
    int seg = blockIdx.y;
    const float* W; unsigned short* WT; int K, N;
    switch (seg) {
        case 0:  W = s0; WT = d0; K = 192; N = 576; break;
        case 1:  W = s1; WT = d1; K = 192; N = 576; break;
        case 2:  W = s2; WT = d2; K = 192; N = 192; break;
        case 3:  W = s3; WT = d3; K = 192; N = 192; break;
        case 4:  W = s4; WT = d4; K = 192; N = 768; break;
        default: W = s5; WT = d5; K = 768; N = 192; break;
    }
    int i = blockIdx.x * 256 + threadIdx.x;
    if (i >= N * K) return;
    int n = i / K, k = i - n * K;
    WT[i] = f2bf(W[(size_t)k * N + n]);
}

// ---------------- bias(+mask) table baked into MFMA C-fragment layout ----------------
__global__ void bias_kernel(const float* __restrict__ bt0, const float* __restrict__ bt1,
                            float* __restrict__ bm) {
    int idx = blockIdx.x * 256 + threadIdx.x;   // 0..24575
    int variant = blockIdx.y;
    const float* bt = variant ? bt1 : bt0;
    int r = idx & 3, lane = (idx >> 2) & 63, ni = (idx >> 8) & 3, mi = (idx >> 10) & 3, h = idx >> 12;
    int g = lane >> 4;
    int q = ni * 16 + (lane & 15);
    int k = mi * 16 + g * 4 + r;
    float v = 0.f;
    if (q < 49 && k < 49) {
        int qh = q / 7, qw = q - qh * 7, kh = k / 7, kw = k - kh * 7;
        v = bt[((qh - kh + 6) * 13 + (qw - kw + 6)) * 6 + h];
        if (variant) {
            int rq = 2 * (qh >= 4) + (qw >= 4), rk = 2 * (kh >= 4) + (kw >= 4);
            if (rq != rk) v -= 100.f;
        }
    }
    bm[(size_t)variant * 24576 + idx] = v;
}

// ---------------- vectorized LayerNorm: 32 lanes/token, 6 consecutive ch/lane ----------
template<int IN_BF16, int ROLL>
__global__ __launch_bounds__(256) void ln_kernel(const void* __restrict__ in,
                                                 unsigned short* __restrict__ out,
                                                 const float* __restrict__ g,
                                                 const float* __restrict__ b) {
    int t   = threadIdx.x;
    int tok = blockIdx.x * 8 + (t >> 5);
    int li  = t & 31;
    int e0  = li * 6;
    int src = tok;
    if (ROLL) {
        int win = tok / 49, p2 = tok - win * 49;
        int h = p2 / 7, w = p2 - h * 7;
        int h2 = h + 3; if (h2 >= 7) h2 -= 7;
        int w2 = w + 3; if (w2 >= 7) w2 -= 7;
        src = win * 49 + h2 * 7 + w2;
    }
    float x[6];
    if (IN_BF16) {
        const unsigned short* p = (const unsigned short*)in + (size_t)src * 192 + e0;
        unsigned int u0 = *(const unsigned int*)(p);
        unsigned int u1 = *(const unsigned int*)(p + 2);
        unsigned int u2 = *(const unsigned int*)(p + 4);
        x[0] = bf2f(u0 & 0xffffu); x[1] = bf2f(u0 >> 16);
        x[2] = bf2f(u1 & 0xffffu); x[3] = bf2f(u1 >> 16);
        x[4] = bf2f(u2 & 0xffffu); x[5] = bf2f(u2 >> 16);
    } else {
        const float* p = (const float*)in + (size_t)src * 192 + e0;   // 8B-aligned (stride 24B)
        float2 a = *(const float2*)(p);
        float2 c = *(const float2*)(p + 2);
        float2 d = *(const float2*)(p + 4);
        x[0] = a.x; x[1] = a.y; x[2] = c.x; x[3] = c.y; x[4] = d.x; x[5] = d.y;
    }
    float s = 0.f, sq = 0.f;
    #pragma unroll
    for (int j = 0; j < 6; ++j) { s += x[j]; sq += x[j] * x[j]; }
    #pragma unroll
    for (int o = 16; o; o >>= 1) { s += __shfl_xor(s, o); sq += __shfl_xor(sq, o); }
    float m   = s * (1.f / 192.f);
    float var = sq * (1.f / 192.f) - m * m;
    float r   = rsqrtf(var + 1e-5f);
    float gv[6], bv[6];
    #pragma unroll
    for (int j = 0; j < 6; ++j) { gv[j] = g[e0 + j]; bv[j] = b[e0 + j]; }
    unsigned short* q = out + (size_t)tok * 192 + e0;
    #pragma unroll
    for (int j = 0; j < 3; ++j) {
        float y0 = (x[2 * j]     - m) * r * gv[2 * j]     + bv[2 * j];
        float y1 = (x[2 * j + 1] - m) * r * gv[2 * j + 1] + bv[2 * j + 1];
        *(unsigned int*)(q + 2 * j) = pack2bf(y0, y1);
    }
}

// ---------------- epilogue codes ----------------
#define EP_QKV        0   // + bias, Q cols pre-scaled by 1/sqrt(dh) -> bf16 (ld = NDIM)
#define EP_MLP1       3   // + bias, fast GELU -> bf16 (ld = NDIM)
#define EP_MLP2_TRUNK 4   // + bias + bf16 residual -> bf16 trunk, LINEAR write
#define EP_MLP2_OUT   5   // + bias + bf16 residual -> f32 d_out with final roll (w+3, c+3)

// ---------------- unified GEMM: C[M,N] = A[M,K] @ W[K,N] + bias, fused epilogues ----
// Tile 128x96, BK=32, 4 waves (2m x 2n), per-wave 64x48 = 4x3 fragments.
// Staging via global_load_lds width=16 (guide m97/m151/m193): double-buffered
// UNPADDED LDS [2][128][32]/[2][96][32]; one barrier per K-step; loads for tile
// kt+1 fly under MFMA of tile kt (drained by the next barrier's vmcnt(0)).
// Bank conflicts handled per rule #21: linear LDS dest + inverse-swizzled global
// SOURCE (slot = (l&3)^((l>>3)&3)) + swizzled READ (slot = kq^((lr>>1)&3));
// resulting read aliasing is 2-way = free. y-fastest + XCD chunking.
template<int NDIM, int KDIM, int NY, int EP>
__global__ __launch_bounds__(256) void gemm_kernel(const unsigned short* __restrict__ A,
                                                   const unsigned short* __restrict__ WT,
                                                   const float* __restrict__ bias,
                                                   const void* __restrict__ res,
                                                   void* __restrict__ out,
                                                   int row0) {
    __shared__ __align__(16) unsigned short As[2][128][32];
    __shared__ __align__(16) unsigned short Bs[2][96][32];
    int tid = threadIdx.x;
    int nwg = gridDim.x;
    int id = blockIdx.x;
    int id2 = (id & 7) * (nwg >> 3) + (id >> 3);    // XCD-chunked (nwg % 8 == 0)
    int by = id2 % NY, bx = id2 / NY;               // y fastest
    int rowBase = bx * 128;
    int colBase = by * 96;

    int wave = tid >> 6, lane = tid & 63;
    int grow  = lane >> 2;                          // row within a 16-row issue
    int gslot = (lane & 3) ^ ((lane >> 3) & 3);     // inverse-swizzled 16B slot
    const unsigned short* Ag = A  + (size_t)rowBase * KDIM + gslot * 8;
    const unsigned short* Bg = WT + (size_t)colBase * KDIM + gslot * 8;

    const int NT = KDIM / 32;

    // wave w stages A rows [32w,32w+32) and (w<3) B rows [32w,32w+32)
    #define STAGE(buf, k0)                                                            \
        do {                                                                          \
            int qa = wave * 32;                                                       \
            GLOAD16(Ag + (size_t)(qa + grow) * KDIM + (k0),      &As[buf][qa][0]);    \
            GLOAD16(Ag + (size_t)(qa + 16 + grow) * KDIM + (k0), &As[buf][qa + 16][0]); \
            if (wave < 3) {                                                           \
                GLOAD16(Bg + (size_t)(qa + grow) * KDIM + (k0),      &Bs[buf][qa][0]);    \
                GLOAD16(Bg + (size_t)(qa + 16 + grow) * KDIM + (k0), &Bs[buf][qa + 16][0]); \
            }                                                                         \
        } while (0)

    STAGE(0, 0);

    int wm = wave >> 1, wn = wave & 1;
    int kq = lane >> 4, lr = lane & 15;
    int sa = (kq ^ ((lr >> 1) & 3)) * 8;            // swizzled read slot offset

    f32x4_t acc[4][3] = {};
    int buf = 0;
    for (int kt = 0; kt < NT; ++kt) {
        __syncthreads();                            // vmcnt(0): tile kt landed in buf
        if (kt + 1 < NT) STAGE(buf ^ 1, (kt + 1) * 32);   // flies under MFMA below
        bf16x8_t afr[4], bfr[3];
        #pragma unroll
        for (int mi = 0; mi < 4; ++mi)
            afr[mi] = *(const bf16x8_t*)&As[buf][wm * 64 + mi * 16 + lr][sa];
        #pragma unroll
        for (int ni = 0; ni < 3; ++ni)
            bfr[ni] = *(const bf16x8_t*)&Bs[buf][wn * 48 + ni * 16 + lr][sa];
        #pragma unroll
        for (int mi = 0; mi < 4; ++mi)
            #pragma unroll
            for (int ni = 0; ni < 3; ++ni)
                acc[mi][ni] = __builtin_amdgcn_mfma_f32_16x16x32_bf16(
                    afr[mi], bfr[ni], acc[mi][ni], 0, 0, 0);
        buf ^= 1;
    }
    #undef STAGE

    const unsigned short* resb = (const unsigned short*)res;
    #pragma unroll
    for (int mi = 0; mi < 4; ++mi) {
        #pragma unroll
        for (int ni = 0; ni < 3; ++ni) {
            int col = colBase + wn * 48 + ni * 16 + lr;
            float bcol = bias[col];
            #pragma unroll
            for (int r = 0; r < 4; ++r) {
                int rloc = rowBase + wm * 64 + mi * 16 + kq * 4 + r;
                float v = acc[mi][ni][r] + bcol;
                if (EP == EP_QKV) {
                    if (colBase < 192) v *= 0.17677669529663687f;   // pre-scale Q
                    ((unsigned short*)out)[(size_t)rloc * NDIM + col] = f2bf(v);
                } else if (EP == EP_MLP1) {
                    // fast exact-GELU (tanh form): max |err| ~3e-4 abs, |v|<~2 here.
                    float u2 = v * (1.59576912f + 0.0713548162f * v * v);
                    float e  = __expf(u2);
                    float gl = v - v * __builtin_amdgcn_rcpf(e + 1.f);
                    ((unsigned short*)out)[(size_t)rloc * NDIM + col] = f2bf(gl);
                } else if (EP == EP_MLP2_TRUNK) {
                    v += bf2f((unsigned int)resb[(size_t)rloc * 192 + col]);
                    int grow2 = row0 + rloc;
                    ((unsigned short*)out)[(size_t)grow2 * 192 + col] = f2bf(v);  // bf16 trunk
                } else {  // EP_MLP2_OUT
                    v += bf2f((unsigned int)resb[(size_t)rloc * 192 + col]);
                    int grow2 = row0 + rloc;
                    int win = grow2 / 49, p2 = grow2 - win * 49;
                    int h = p2 / 7, w = p2 - h * 7;
                    int w2 = w + 3; if (w2 >= 7) w2 -= 7;
                    int c2 = col + 3; if (c2 >= 192) c2 -= 192;
                    ((float*)out)[((size_t)win * 49 + h * 7 + w2) * 192 + c2] = v;
                }
            }
        }
    }
}

// ---------------- fused PROJ + residual + LN2: tile 128x192, wave = 32 rows x 192 cols ----
// FROZEN at the R19-passing form (half-split MFMA batch, no launch_bounds cap).
template<int ROLLRES>
__global__ __launch_bounds__(256) void projln_kernel(const unsigned short* __restrict__ A,
                                                     const unsigned short* __restrict__ WT,
                                                     const float* __restrict__ bias,
                                                     const void* __restrict__ res,
                                                     const float* __restrict__ g2,
                                                     const float* __restrict__ b2,
                                                     unsigned short* __restrict__ out) {
    __shared__ __align__(16) unsigned short As[128][40];
    __shared__ __align__(16) unsigned short Bs[192][40];
    int tid = threadIdx.x;
    int nwg = gridDim.x;
    int id = blockIdx.x;
    int bx = (id & 7) * (nwg >> 3) + (id >> 3);     // XCD-chunked
    int rowBase = bx * 128;

    int cr = tid >> 2, cp = (tid & 3) * 8;
    const unsigned short* Ab = A  + (size_t)rowBase * 192 + cp;
    const unsigned short* Bb = WT + cp;

    uint4 a0, a1, b0, b1, b2r;
    #define LOADK(k0)                                                          \
        do {                                                                   \
            a0  = *(const uint4*)(Ab + (size_t)cr * 192 + (k0));               \
            a1  = *(const uint4*)(Ab + (size_t)(cr + 64) * 192 + (k0));        \
            b0  = *(const uint4*)(Bb + (size_t)cr * 192 + (k0));               \
            b1  = *(const uint4*)(Bb + (size_t)(cr + 64) * 192 + (k0));        \
            b2r = *(const uint4*)(Bb + (size_t)(cr + 128) * 192 + (k0));       \
        } while (0)
    #define WRITEK()                                                           \
        do {                                                                   \
            *(uint4*)&As[cr][cp] = a0;                                         \
            *(uint4*)&As[cr + 64][cp] = a1;                                    \
            *(uint4*)&Bs[cr][cp] = b0;                                         \
            *(uint4*)&Bs[cr + 64][cp] = b1;                                    \
            *(uint4*)&Bs[cr + 128][cp] = b2r;                                  \
        } while (0)

    LOADK(0);

    int wave = tid >> 6, lane = tid & 63;
    int wm = wave;                                   // 4 waves x 32 rows
    int kq = lane >> 4, lr = lane & 15;

    f32x4_t acc[2][12] = {};
    for (int kt = 0; kt < 6; ++kt) {
        __syncthreads();
        WRITEK();
        if (kt + 1 < 6) LOADK((kt + 1) * 32);
        __syncthreads();
        bf16x8_t afr[2];
        #pragma unroll
        for (int mi = 0; mi < 2; ++mi)
            afr[mi] = *(const bf16x8_t*)&As[wm * 32 + mi * 16 + lr][kq * 8];
        #pragma unroll
        for (int half = 0; half < 2; ++half) {
            bf16x8_t bfr[6];
            #pragma unroll
            for (int ni = 0; ni < 6; ++ni)
                bfr[ni] = *(const bf16x8_t*)&Bs[(half * 6 + ni) * 16 + lr][kq * 8];
            #pragma unroll
            for (int mi = 0; mi < 2; ++mi)
                #pragma unroll
                for (int ni = 0; ni < 6; ++ni)
                    acc[mi][half * 6 + ni] = __builtin_amdgcn_mfma_f32_16x16x32_bf16(
                        afr[mi], bfr[ni], acc[mi][half * 6 + ni], 0, 0, 0);
        }
    }
    #undef LOADK
    #undef WRITEK

    const float* resf = (const float*)res;
    const unsigned short* resb = (const unsigned short*)res;
    float biasv[12], g2v[12], b2v[12];
    #pragma unroll
    for (int ni = 0; ni < 12; ++ni) {
        int col = ni * 16 + lr;
        biasv[ni] = bias[col]; g2v[ni] = g2[col]; b2v[ni] = b2[col];
    }

    #pragma unroll
    for (int mi = 0; mi < 2; ++mi) {
        #pragma unroll
        for (int r = 0; r < 4; ++r) {
            int rloc = rowBase + wm * 32 + mi * 16 + kq * 4 + r;
            size_t rsrc = rloc;
            if (ROLLRES) {
                int win = rloc / 49, p2 = rloc - win * 49;
                int h = p2 / 7, w = p2 - h * 7;
                int h2 = h + 3; if (h2 >= 7) h2 -= 7;
                int w2 = w + 3; if (w2 >= 7) w2 -= 7;
                rsrc = (size_t)win * 49 + h2 * 7 + w2;
            }
            float v[12], s = 0.f, sq = 0.f;
            #pragma unroll
            for (int ni = 0; ni < 12; ++ni) {
                int col = ni * 16 + lr;
                float t = acc[mi][ni][r] + biasv[ni];
                t += ROLLRES ? bf2f((unsigned int)resb[rsrc * 192 + col])
                             : resf[rsrc * 192 + col];
                v[ni] = t; s += t; sq += t * t;
            }
            s  += __shfl_xor(s, 1);  s  += __shfl_xor(s, 2);
            s  += __shfl_xor(s, 4);  s  += __shfl_xor(s, 8);
            sq += __shfl_xor(sq, 1); sq += __shfl_xor(sq, 2);
            sq += __shfl_xor(sq, 4); sq += __shfl_xor(sq, 8);
            float mean = s * (1.f / 192.f);
            float var  = sq * (1.f / 192.f) - mean * mean;
            float rstd = rsqrtf(var + 1e-5f);
            unsigned short* op = out + (size_t)rloc * 192;
            #pragma unroll
            for (int ni = 0; ni < 12; ++ni) {
                int col = ni * 16 + lr;
                op[col] = f2bf((v[ni] - mean) * rstd * g2v[ni] + b2v[ni]);
            }
        }
    }
}

// ---------------- MFMA window attention: 1 wave per (head, window) ----------------
__global__ __launch_bounds__(64) void attn_kernel(const unsigned short* __restrict__ qkv,
                                                  const float* __restrict__ bm,  // [6][4][4][64][4]
                                                  unsigned short* __restrict__ outp,
                                                  int win0) {
    __shared__ unsigned short P[64][72];
    __shared__ unsigned short VT[32][72];
    int head = blockIdx.x, wloc = blockIdx.y;
    int lane = threadIdx.x;
    int g = lane >> 4, lr = lane & 15;
    const unsigned short* base = qkv + (size_t)wloc * 49 * 576;

    // stage V^T (tok>=49 -> zeros)
    for (int i = lane; i < 256; i += 64) {
        int tok = i >> 2, seg = i & 3;
        uint4 u = make_uint4(0u, 0u, 0u, 0u);
        if (tok < 49)
            u = *(const uint4*)(base + (size_t)tok * 576 + 384 + head * 32 + seg * 8);
        const unsigned short* us = (const unsigned short*)&u;
        #pragma unroll
        for (int j = 0; j < 8; ++j) VT[seg * 8 + j][tok] = us[j];
    }

    bf16x8_t kf[4], qf[4];
    #pragma unroll
    for (int mi = 0; mi < 4; ++mi) {
        int tok = mi * 16 + lr; if (tok > 48) tok = 48;
        kf[mi] = *(const bf16x8_t*)(base + (size_t)tok * 576 + 192 + head * 32 + g * 8);
    }
    #pragma unroll
    for (int ni = 0; ni < 4; ++ni) {
        int tok = ni * 16 + lr; if (tok > 48) tok = 48;
        qf[ni] = *(const bf16x8_t*)(base + (size_t)tok * 576 + head * 32 + g * 8);
    }

    const float* bmh = bm + (size_t)head * 4096;
    f32x4_t acc[4][4];
    #pragma unroll
    for (int mi = 0; mi < 4; ++mi)
        #pragma unroll
        for (int ni = 0; ni < 4; ++ni)
            acc[mi][ni] = *(const f32x4_t*)(bmh + ((mi * 4 + ni) * 64 + lane) * 4);
    __builtin_amdgcn_s_setprio(1);   // T5: favor MFMA wave vs other blocks' loads
    #pragma unroll
    for (int mi = 0; mi < 4; ++mi)
        #pragma unroll
        for (int ni = 0; ni < 4; ++ni)
            acc[mi][ni] = __builtin_amdgcn_mfma_f32_16x16x32_bf16(kf[mi], qf[ni], acc[mi][ni], 0, 0, 0);
    __builtin_amdgcn_s_setprio(0);

    float inv[4];
    #pragma unroll
    for (int ni = 0; ni < 4; ++ni) {
        float mx = -1e30f;
        #pragma unroll
        for (int mi = 0; mi < 3; ++mi)
            #pragma unroll
            for (int r = 0; r < 4; ++r) mx = fmaxf(mx, acc[mi][ni][r]);
        mx = fmaxf(mx, (g == 0) ? acc[3][ni][0] : -1e30f);
        mx = fmaxf(mx, __shfl_xor(mx, 16));
        mx = fmaxf(mx, __shfl_xor(mx, 32));
        float p[16], ss = 0.f;
        #pragma unroll
        for (int mi = 0; mi < 3; ++mi)
            #pragma unroll
            for (int r = 0; r < 4; ++r) {
                float e = __expf(acc[mi][ni][r] - mx);
                p[mi * 4 + r] = e; ss += e;
            }
        float e48 = (g == 0) ? __expf(acc[3][ni][0] - mx) : 0.f;
        p[12] = e48; p[13] = p[14] = p[15] = 0.f; ss += e48;
        ss += __shfl_xor(ss, 16);
        ss += __shfl_xor(ss, 32);
        inv[ni] = 1.f / ss;
        int q = ni * 16 + lr;
        #pragma unroll
        for (int mi = 0; mi < 4; ++mi) {
            *(unsigned int*)&P[q][mi * 16 + g * 4]     = pack2bf(p[mi * 4 + 0], p[mi * 4 + 1]);
            *(unsigned int*)&P[q][mi * 16 + g * 4 + 2] = pack2bf(p[mi * 4 + 2], p[mi * 4 + 3]);
        }
    }
    __syncthreads();

    f32x4_t oacc[2][4] = {};
    #pragma unroll
    for (int kt = 0; kt < 2; ++kt) {
        bf16x8_t va[2], pb[4];
        #pragma unroll
        for (int mt = 0; mt < 2; ++mt)
            va[mt] = *(const bf16x8_t*)&VT[mt * 16 + lr][kt * 32 + g * 8];
        #pragma unroll
        for (int nt = 0; nt < 4; ++nt)
            pb[nt] = *(const bf16x8_t*)&P[nt * 16 + lr][kt * 32 + g * 8];
        __builtin_amdgcn_s_setprio(1);
        #pragma unroll
        for (int mt = 0; mt < 2; ++mt)
            #pragma unroll
            for (int nt = 0; nt < 4; ++nt)
                oacc[mt][nt] = __builtin_amdgcn_mfma_f32_16x16x32_bf16(va[mt], pb[nt], oacc[mt][nt], 0, 0, 0);
        __builtin_amdgcn_s_setprio(0);
    }

    #pragma unroll
    for (int nt = 0; nt < 4; ++nt) {
        int q = nt * 16 + lr;
        if (q < 49) {
            size_t tokg = (size_t)(win0 + wloc) * 49 + q;
            unsigned short* op = outp + tokg * 192 + head * 32;
            #pragma unroll
            for (int mt = 0; mt < 2; ++mt) {
                int d0 = mt * 16 + g * 4;
                float a0 = oacc[mt][nt][0] * inv[nt], a1 = oacc[mt][nt][1] * inv[nt];
                float a2 = oacc[mt][nt][2] * inv[nt], a3 = oacc[mt][nt][3] * inv[nt];
                *(unsigned int*)(op + d0)     = pack2bf(a0, a1);
                *(unsigned int*)(op + d0 + 2) = pack2bf(a2, a3);
            }
        }
    }
}

// ---------------- host launch ----------------
extern "C" void kernel_launch(void* const* d_in, const int* in_sizes, int n_in,
                              void* d_out, int out_size, void* d_ws, size_t ws_size,
                              hipStream_t stream) {
    (void)in_sizes; (void)n_in; (void)out_size; (void)ws_size;
    const float* X     = (const float*)d_in[0];
    const float* ln1_g = (const float*)d_in[1];
    const float* ln1_b = (const float*)d_in[2];
    const float* ln2_g = (const float*)d_in[3];
    const float* ln2_b = (const float*)d_in[4];
    const float* qkv_w[2]  = { (const float*)d_in[5],  (const float*)d_in[10] };
    const float* qkv_b[2]  = { (const float*)d_in[6],  (const float*)d_in[11] };
    const float* proj_w[2] = { (const float*)d_in[7],  (const float*)d_in[12] };
    const float* proj_b[2] = { (const float*)d_in[8],  (const float*)d_in[13] };
    const float* btab[2]   = { (const float*)d_in[9],  (const float*)d_in[14] };
    const float* w1 = (const float*)d_in[15];
    const float* b1 = (const float*)d_in[16];
    const float* w2 = (const float*)d_in[17];
    const float* b2 = (const float*)d_in[18];

    char* p = (char*)d_ws;
    auto takeb = [&](size_t bytes) -> char* {
        char* r = p;
        p += (bytes + 255) & ~(size_t)255;
        return r;
    };
    auto take = [&](size_t elems) -> unsigned short* {
        return (unsigned short*)takeb(elems * 2);
    };
    unsigned short* WTq[2]; unsigned short* WTp[2];
    WTq[0] = take(576 * 192); WTp[0] = take(192 * 192);
    WTq[1] = take(576 * 192); WTp[1] = take(192 * 192);
    unsigned short* WT1 = take(768 * 192);
    unsigned short* WT2 = take(192 * 768);
    float* biasM = (float*)takeb(2 * 24576 * sizeof(float));
    unsigned short* B0 = take((size_t)NTOK * 192);            // ln1 out -> attn out -> ln2 out (fused)
    unsigned short* B1 = take((size_t)TOK_PER_CHUNK * 768);   // qkv chunk / mlp hidden chunk
    unsigned short* TK = take((size_t)NTOK * 192);            // bf16 trunk (block-1 frame, LINEAR)

    wt_all_kernel<<<dim3(576, 6), dim3(256), 0, stream>>>(
        qkv_w[0], qkv_w[1], proj_w[0], proj_w[1], w1, w2,
        WTq[0], WTq[1], WTp[0], WTp[1], WT1, WT2);
    bias_kernel<<<dim3(96, 2), dim3(256), 0, stream>>>(btab[0], btab[1], biasM);

    for (int blk = 0; blk < 2; ++blk) {
        // LN1: blk0 reads f32 input X (linear); blk1 reads bf16 trunk (roll-read)
        if (blk == 0)
            ln_kernel<0, 0><<<dim3(NTOK / 8), dim3(256), 0, stream>>>((const void*)X, B0, ln1_g, ln1_b);
        else
            ln_kernel<1, 1><<<dim3(NTOK / 8), dim3(256), 0, stream>>>((const void*)TK, B0, ln1_g, ln1_b);

        for (int c = 0; c < NCHUNK; ++c) {
            int row0 = c * TOK_PER_CHUNK;
            gemm_kernel<576, 192, 6, EP_QKV><<<dim3((TOK_PER_CHUNK / 128) * 6), dim3(256), 0, stream>>>(
                B0 + (size_t)row0 * 192, WTq[blk], qkv_b[blk], nullptr, (void*)B1, row0);
            attn_kernel<<<dim3(6, WIN_PER_CHUNK), dim3(64), 0, stream>>>(
                B1, biasM + (size_t)blk * 24576, B0, c * WIN_PER_CHUNK);
        }

        // Fused PROJ + residual + LN2: A=B0 (attn out), writes post-LN2 B0 in place.
        // Residual: blk0 = X (f32, linear), blk1 = TK (bf16, roll-read).
        if (blk == 0)
            projln_kernel<0><<<dim3(NTOK / 128), dim3(256), 0, stream>>>(
                B0, WTp[blk], proj_b[blk], (const void*)X, ln2_g, ln2_b, B0);
        else
            projln_kernel<1><<<dim3(NTOK / 128), dim3(256), 0, stream>>>(
                B0, WTp[blk], proj_b[blk], (const void*)TK, ln2_g, ln2_b, B0);

        for (int c = 0; c < NCHUNK; ++c) {
            int row0 = c * TOK_PER_CHUNK;
            gemm_kernel<768, 192, 8, EP_MLP1><<<dim3((TOK_PER_CHUNK / 128) * 8), dim3(256), 0, stream>>>(
                B0 + (size_t)row0 * 192, WT1, b1, nullptr, (void*)B1, row0);
            if (blk == 0)
                gemm_kernel<192, 768, 2, EP_MLP2_TRUNK><<<dim3((TOK_PER_CHUNK / 128) * 2), dim3(256), 0, stream>>>(
                    B1, WT2, b2, (const void*)(B0 + (size_t)row0 * 192), (void*)TK, row0);
            else
                gemm_kernel<192, 768, 2, EP_MLP2_OUT><<<dim3((TOK_PER_CHUNK / 128) * 2), dim3(256), 0, stream>>>(
                    B1, WT2, b2, (const void*)(B0 + (size_t)row0 * 192), (void*)d_out, row0);
        }
    }
}

// Round 21
// 2468.381 us; speedup vs baseline: 1.0563x; 1.0563x over previous
//
#include <hip/hip_runtime.h>
#include <hip/hip_bf16.h>
#include <math.h>

// ---------------- problem constants ----------------
#define NTOK 401408              // 8*1024*49 tokens
#define NWIN 8192                // 8*1024 windows
#define NCHUNK 4
#define TOK_PER_CHUNK (NTOK / NCHUNK)   // 100352
#define WIN_PER_CHUNK (NWIN / NCHUNK)   // 2048

typedef __attribute__((ext_vector_type(8))) short bf16x8_t;
typedef __attribute__((ext_vector_type(4))) float f32x4_t;

__device__ __forceinline__ float bf2f(unsigned int u) {
    return __uint_as_float(u << 16);
}
__device__ __forceinline__ unsigned short f2bf(float f) {
    unsigned int x = __float_as_uint(f);
    x += 0x7fffu + ((x >> 16) & 1u);   // RNE
    return (unsigned short)(x >> 16);
}
__device__ __forceinline__ unsigned int pack2bf(float a, float b) {
    return (unsigned int)f2bf(a) | ((unsigned int)f2bf(b) << 16);
}

// ---------------- all weight transposes in one dispatch:  WT[n][k] = W[k][n] ------
__global__ void wt_all_kernel(const float* __restrict__ s0, const float* __restrict__ s1,
                              const float* __restrict__ s2, const float* __restrict__ s3,
                              const float* __restrict__ s4, const float* __restrict__ s5,
                              unsigned short* __restrict__ d0, unsigned short* __restrict__ d1,
                              unsigned short* __restrict__ d2, unsigned short* __restrict__ d3,
                              unsigned short* __restrict__ d4, unsigned short* __restrict__ d5) {
    int seg = blockIdx.y;
    const float* W; unsigned short* WT; int K, N;
    switch (seg) {
        case 0:  W = s0; WT = d0; K = 192; N = 576; break;
        case 1:  W = s1; WT = d1; K = 192; N = 576; break;
        case 2:  W = s2; WT = d2; K = 192; N = 192; break;
        case 3:  W = s3; WT = d3; K = 192; N = 192; break;
        case 4:  W = s4; WT = d4; K = 192; N = 768; break;
        default: W = s5; WT = d5; K = 768; N = 192; break;
    }
    int i = blockIdx.x * 256 + threadIdx.x;
    if (i >= N * K) return;
    int n = i / K, k = i - n * K;
    WT[i] = f2bf(W[(size_t)k * N + n]);
}

// ---------------- bias(+mask) table baked into MFMA C-fragment layout ----------------
__global__ void bias_kernel(const float* __restrict__ bt0, const float* __restrict__ bt1,
                            float* __restrict__ bm) {
    int idx = blockIdx.x * 256 + threadIdx.x;   // 0..24575
    int variant = blockIdx.y;
    const float* bt = variant ? bt1 : bt0;
    int r = idx & 3, lane = (idx >> 2) & 63, ni = (idx >> 8) & 3, mi = (idx >> 10) & 3, h = idx >> 12;
    int g = lane >> 4;
    int q = ni * 16 + (lane & 15);
    int k = mi * 16 + g * 4 + r;
    float v = 0.f;
    if (q < 49 && k < 49) {
        int qh = q / 7, qw = q - qh * 7, kh = k / 7, kw = k - kh * 7;
        v = bt[((qh - kh + 6) * 13 + (qw - kw + 6)) * 6 + h];
        if (variant) {
            int rq = 2 * (qh >= 4) + (qw >= 4), rk = 2 * (kh >= 4) + (kw >= 4);
            if (rq != rk) v -= 100.f;
        }
    }
    bm[(size_t)variant * 24576 + idx] = v;
}

// ---------------- vectorized LayerNorm: 32 lanes/token, 6 consecutive ch/lane ----------
template<int IN_BF16, int ROLL>
__global__ __launch_bounds__(256) void ln_kernel(const void* __restrict__ in,
                                                 unsigned short* __restrict__ out,
                                                 const float* __restrict__ g,
                                                 const float* __restrict__ b) {
    int t   = threadIdx.x;
    int tok = blockIdx.x * 8 + (t >> 5);
    int li  = t & 31;
    int e0  = li * 6;
    int src = tok;
    if (ROLL) {
        int win = tok / 49, p2 = tok - win * 49;
        int h = p2 / 7, w = p2 - h * 7;
        int h2 = h + 3; if (h2 >= 7) h2 -= 7;
        int w2 = w + 3; if (w2 >= 7) w2 -= 7;
        src = win * 49 + h2 * 7 + w2;
    }
    float x[6];
    if (IN_BF16) {
        const unsigned short* p = (const unsigned short*)in + (size_t)src * 192 + e0;
        unsigned int u0 = *(const unsigned int*)(p);
        unsigned int u1 = *(const unsigned int*)(p + 2);
        unsigned int u2 = *(const unsigned int*)(p + 4);
        x[0] = bf2f(u0 & 0xffffu); x[1] = bf2f(u0 >> 16);
        x[2] = bf2f(u1 & 0xffffu); x[3] = bf2f(u1 >> 16);
        x[4] = bf2f(u2 & 0xffffu); x[5] = bf2f(u2 >> 16);
    } else {
        const float* p = (const float*)in + (size_t)src * 192 + e0;   // 8B-aligned (stride 24B)
        float2 a = *(const float2*)(p);
        float2 c = *(const float2*)(p + 2);
        float2 d = *(const float2*)(p + 4);
        x[0] = a.x; x[1] = a.y; x[2] = c.x; x[3] = c.y; x[4] = d.x; x[5] = d.y;
    }
    float s = 0.f, sq = 0.f;
    #pragma unroll
    for (int j = 0; j < 6; ++j) { s += x[j]; sq += x[j] * x[j]; }
    #pragma unroll
    for (int o = 16; o; o >>= 1) { s += __shfl_xor(s, o); sq += __shfl_xor(sq, o); }
    float m   = s * (1.f / 192.f);
    float var = sq * (1.f / 192.f) - m * m;
    float r   = rsqrtf(var + 1e-5f);
    float gv[6], bv[6];
    #pragma unroll
    for (int j = 0; j < 6; ++j) { gv[j] = g[e0 + j]; bv[j] = b[e0 + j]; }
    unsigned short* q = out + (size_t)tok * 192 + e0;
    #pragma unroll
    for (int j = 0; j < 3; ++j) {
        float y0 = (x[2 * j]     - m) * r * gv[2 * j]     + bv[2 * j];
        float y1 = (x[2 * j + 1] - m) * r * gv[2 * j + 1] + bv[2 * j + 1];
        *(unsigned int*)(q + 2 * j) = pack2bf(y0, y1);
    }
}

// ---------------- epilogue codes ----------------
#define EP_QKV        0   // + bias, Q cols pre-scaled by 1/sqrt(dh) -> bf16 (ld = NDIM)
#define EP_MLP1       3   // + bias, fast GELU -> bf16 (ld = NDIM)
#define EP_MLP2_TRUNK 4   // + bias + bf16 residual -> bf16 trunk, LINEAR write
#define EP_MLP2_OUT   5   // + bias + bf16 residual -> f32 d_out with final roll (w+3, c+3)

// ---------------- unified GEMM: C[M,N] = A[M,K] @ W[K,N] + bias, fused epilogues ----
// Tile 128x96, BK=32, 4 waves (2m x 2n), per-wave 64x48 = 4x3 fragments.
// SINGLE-buffered LDS (17.9 KB -> high occupancy); register prefetch of next
// K-slice flies across the barrier + MFMA phase. y-fastest + XCD chunking.
// (R20 A/B: global_load_lds + dbuf 28KB regressed +133us — occupancy beats
//  staging efficiency in this latency-bound regime. Keep this form.)
template<int NDIM, int KDIM, int NY, int EP>
__global__ __launch_bounds__(256) void gemm_kernel(const unsigned short* __restrict__ A,
                                                   const unsigned short* __restrict__ WT,
                                                   const float* __restrict__ bias,
                                                   const void* __restrict__ res,
                                                   void* __restrict__ out,
                                                   int row0) {
    __shared__ __align__(16) unsigned short As[128][40];   // +8 pad
    __shared__ __align__(16) unsigned short Bs[96][40];
    int tid = threadIdx.x;
    int nwg = gridDim.x;
    int id = blockIdx.x;
    int id2 = (id & 7) * (nwg >> 3) + (id >> 3);    // XCD-chunked (nwg % 8 == 0)
    int by = id2 % NY, bx = id2 / NY;               // y fastest
    int rowBase = bx * 128;
    int colBase = by * 96;

    int cr = tid >> 2, cp = (tid & 3) * 8;          // chunk row / elem offset
    const unsigned short* Ab = A  + (size_t)rowBase * KDIM + cp;
    const unsigned short* Bb = WT + (size_t)colBase * KDIM + cp;

    uint4 a0, a1, b0, b1;
    const int NT = KDIM / 32;

    #define LOADK(k0)                                                          \
        do {                                                                   \
            a0 = *(const uint4*)(Ab + (size_t)cr * KDIM + (k0));               \
            a1 = *(const uint4*)(Ab + (size_t)(cr + 64) * KDIM + (k0));        \
            b0 = *(const uint4*)(Bb + (size_t)cr * KDIM + (k0));               \
            if (tid < 128) b1 = *(const uint4*)(Bb + (size_t)(cr + 64) * KDIM + (k0)); \
        } while (0)
    #define WRITEK()                                                           \
        do {                                                                   \
            *(uint4*)&As[cr][cp] = a0;                                         \
            *(uint4*)&As[cr + 64][cp] = a1;                                    \
            *(uint4*)&Bs[cr][cp] = b0;                                         \
            if (tid < 128) *(uint4*)&Bs[cr + 64][cp] = b1;                     \
        } while (0)

    LOADK(0);

    int wave = tid >> 6, lane = tid & 63;
    int wm = wave >> 1, wn = wave & 1;
    int kq = lane >> 4, lr = lane & 15;

    f32x4_t acc[4][3] = {};
    for (int kt = 0; kt < NT; ++kt) {
        __syncthreads();                            // previous tile fully consumed
        WRITEK();
        if (kt + 1 < NT) LOADK((kt + 1) * 32);      // next slice in flight during MFMA
        __syncthreads();                            // tile fully written
        bf16x8_t afr[4], bfr[3];
        #pragma unroll
        for (int mi = 0; mi < 4; ++mi)
            afr[mi] = *(const bf16x8_t*)&As[wm * 64 + mi * 16 + lr][kq * 8];
        #pragma unroll
        for (int ni = 0; ni < 3; ++ni)
            bfr[ni] = *(const bf16x8_t*)&Bs[wn * 48 + ni * 16 + lr][kq * 8];
        #pragma unroll
        for (int mi = 0; mi < 4; ++mi)
            #pragma unroll
            for (int ni = 0; ni < 3; ++ni)
                acc[mi][ni] = __builtin_amdgcn_mfma_f32_16x16x32_bf16(
                    afr[mi], bfr[ni], acc[mi][ni], 0, 0, 0);
    }
    #undef LOADK
    #undef WRITEK

    const unsigned short* resb = (const unsigned short*)res;
    #pragma unroll
    for (int mi = 0; mi < 4; ++mi) {
        #pragma unroll
        for (int ni = 0; ni < 3; ++ni) {
            int col = colBase + wn * 48 + ni * 16 + lr;
            float bcol = bias[col];
            #pragma unroll
            for (int r = 0; r < 4; ++r) {
                int rloc = rowBase + wm * 64 + mi * 16 + kq * 4 + r;
                float v = acc[mi][ni][r] + bcol;
                if (EP == EP_QKV) {
                    if (colBase < 192) v *= 0.17677669529663687f;   // pre-scale Q
                    ((unsigned short*)out)[(size_t)rloc * NDIM + col] = f2bf(v);
                } else if (EP == EP_MLP1) {
                    // fast exact-GELU (tanh form): max |err| ~3e-4 abs, |v|<~2 here.
                    float u2 = v * (1.59576912f + 0.0713548162f * v * v);
                    float e  = __expf(u2);
                    float gl = v - v * __builtin_amdgcn_rcpf(e + 1.f);
                    ((unsigned short*)out)[(size_t)rloc * NDIM + col] = f2bf(gl);
                } else if (EP == EP_MLP2_TRUNK) {
                    v += bf2f((unsigned int)resb[(size_t)rloc * 192 + col]);
                    int grow = row0 + rloc;
                    ((unsigned short*)out)[(size_t)grow * 192 + col] = f2bf(v);  // bf16 trunk
                } else {  // EP_MLP2_OUT
                    v += bf2f((unsigned int)resb[(size_t)rloc * 192 + col]);
                    int grow = row0 + rloc;
                    int win = grow / 49, p2 = grow - win * 49;
                    int h = p2 / 7, w = p2 - h * 7;
                    int w2 = w + 3; if (w2 >= 7) w2 -= 7;
                    int c2 = col + 3; if (c2 >= 192) c2 -= 192;
                    ((float*)out)[((size_t)win * 49 + h * 7 + w2) * 192 + c2] = v;
                }
            }
        }
    }
}

// ---------------- fused PROJ + residual + LN2: tile 128x192, wave = 32 rows x 192 cols ----
// FROZEN at the R19-passing form (half-split MFMA batch, no launch_bounds cap).
template<int ROLLRES>
__global__ __launch_bounds__(256) void projln_kernel(const unsigned short* __restrict__ A,
                                                     const unsigned short* __restrict__ WT,
                                                     const float* __restrict__ bias,
                                                     const void* __restrict__ res,
                                                     const float* __restrict__ g2,
                                                     const float* __restrict__ b2,
                                                     unsigned short* __restrict__ out) {
    __shared__ __align__(16) unsigned short As[128][40];
    __shared__ __align__(16) unsigned short Bs[192][40];
    int tid = threadIdx.x;
    int nwg = gridDim.x;
    int id = blockIdx.x;
    int bx = (id & 7) * (nwg >> 3) + (id >> 3);     // XCD-chunked
    int rowBase = bx * 128;

    int cr = tid >> 2, cp = (tid & 3) * 8;
    const unsigned short* Ab = A  + (size_t)rowBase * 192 + cp;
    const unsigned short* Bb = WT + cp;

    uint4 a0, a1, b0, b1, b2r;
    #define LOADK(k0)                                                          \
        do {                                                                   \
            a0  = *(const uint4*)(Ab + (size_t)cr * 192 + (k0));               \
            a1  = *(const uint4*)(Ab + (size_t)(cr + 64) * 192 + (k0));        \
            b0  = *(const uint4*)(Bb + (size_t)cr * 192 + (k0));               \
            b1  = *(const uint4*)(Bb + (size_t)(cr + 64) * 192 + (k0));        \
            b2r = *(const uint4*)(Bb + (size_t)(cr + 128) * 192 + (k0));       \
        } while (0)
    #define WRITEK()                                                           \
        do {                                                                   \
            *(uint4*)&As[cr][cp] = a0;                                         \
            *(uint4*)&As[cr + 64][cp] = a1;                                    \
            *(uint4*)&Bs[cr][cp] = b0;                                         \
            *(uint4*)&Bs[cr + 64][cp] = b1;                                    \
            *(uint4*)&Bs[cr + 128][cp] = b2r;                                  \
        } while (0)

    LOADK(0);

    int wave = tid >> 6, lane = tid & 63;
    int wm = wave;                                   // 4 waves x 32 rows
    int kq = lane >> 4, lr = lane & 15;

    f32x4_t acc[2][12] = {};
    for (int kt = 0; kt < 6; ++kt) {
        __syncthreads();
        WRITEK();
        if (kt + 1 < 6) LOADK((kt + 1) * 32);
        __syncthreads();
        bf16x8_t afr[2];
        #pragma unroll
        for (int mi = 0; mi < 2; ++mi)
            afr[mi] = *(const bf16x8_t*)&As[wm * 32 + mi * 16 + lr][kq * 8];
        #pragma unroll
        for (int half = 0; half < 2; ++half) {
            bf16x8_t bfr[6];
            #pragma unroll
            for (int ni = 0; ni < 6; ++ni)
                bfr[ni] = *(const bf16x8_t*)&Bs[(half * 6 + ni) * 16 + lr][kq * 8];
            #pragma unroll
            for (int mi = 0; mi < 2; ++mi)
                #pragma unroll
                for (int ni = 0; ni < 6; ++ni)
                    acc[mi][half * 6 + ni] = __builtin_amdgcn_mfma_f32_16x16x32_bf16(
                        afr[mi], bfr[ni], acc[mi][half * 6 + ni], 0, 0, 0);
        }
    }
    #undef LOADK
    #undef WRITEK

    const float* resf = (const float*)res;
    const unsigned short* resb = (const unsigned short*)res;
    float biasv[12], g2v[12], b2v[12];
    #pragma unroll
    for (int ni = 0; ni < 12; ++ni) {
        int col = ni * 16 + lr;
        biasv[ni] = bias[col]; g2v[ni] = g2[col]; b2v[ni] = b2[col];
    }

    #pragma unroll
    for (int mi = 0; mi < 2; ++mi) {
        #pragma unroll
        for (int r = 0; r < 4; ++r) {
            int rloc = rowBase + wm * 32 + mi * 16 + kq * 4 + r;
            size_t rsrc = rloc;
            if (ROLLRES) {
                int win = rloc / 49, p2 = rloc - win * 49;
                int h = p2 / 7, w = p2 - h * 7;
                int h2 = h + 3; if (h2 >= 7) h2 -= 7;
                int w2 = w + 3; if (w2 >= 7) w2 -= 7;
                rsrc = (size_t)win * 49 + h2 * 7 + w2;
            }
            float v[12], s = 0.f, sq = 0.f;
            #pragma unroll
            for (int ni = 0; ni < 12; ++ni) {
                int col = ni * 16 + lr;
                float t = acc[mi][ni][r] + biasv[ni];
                t += ROLLRES ? bf2f((unsigned int)resb[rsrc * 192 + col])
                             : resf[rsrc * 192 + col];
                v[ni] = t; s += t; sq += t * t;
            }
            s  += __shfl_xor(s, 1);  s  += __shfl_xor(s, 2);
            s  += __shfl_xor(s, 4);  s  += __shfl_xor(s, 8);
            sq += __shfl_xor(sq, 1); sq += __shfl_xor(sq, 2);
            sq += __shfl_xor(sq, 4); sq += __shfl_xor(sq, 8);
            float mean = s * (1.f / 192.f);
            float var  = sq * (1.f / 192.f) - mean * mean;
            float rstd = rsqrtf(var + 1e-5f);
            unsigned short* op = out + (size_t)rloc * 192;
            #pragma unroll
            for (int ni = 0; ni < 12; ++ni) {
                int col = ni * 16 + lr;
                op[col] = f2bf((v[ni] - mean) * rstd * g2v[ni] + b2v[ni]);
            }
        }
    }
}

// ---------------- MFMA window attention: 1 wave per (head, window) ----------------
__global__ __launch_bounds__(64) void attn_kernel(const unsigned short* __restrict__ qkv,
                                                  const float* __restrict__ bm,  // [6][4][4][64][4]
                                                  unsigned short* __restrict__ outp,
                                                  int win0) {
    __shared__ unsigned short P[64][72];
    __shared__ unsigned short VT[32][72];
    int head = blockIdx.x, wloc = blockIdx.y;
    int lane = threadIdx.x;
    int g = lane >> 4, lr = lane & 15;
    const unsigned short* base = qkv + (size_t)wloc * 49 * 576;

    // stage V^T (tok>=49 -> zeros)
    for (int i = lane; i < 256; i += 64) {
        int tok = i >> 2, seg = i & 3;
        uint4 u = make_uint4(0u, 0u, 0u, 0u);
        if (tok < 49)
            u = *(const uint4*)(base + (size_t)tok * 576 + 384 + head * 32 + seg * 8);
        const unsigned short* us = (const unsigned short*)&u;
        #pragma unroll
        for (int j = 0; j < 8; ++j) VT[seg * 8 + j][tok] = us[j];
    }

    bf16x8_t kf[4], qf[4];
    #pragma unroll
    for (int mi = 0; mi < 4; ++mi) {
        int tok = mi * 16 + lr; if (tok > 48) tok = 48;
        kf[mi] = *(const bf16x8_t*)(base + (size_t)tok * 576 + 192 + head * 32 + g * 8);
    }
    #pragma unroll
    for (int ni = 0; ni < 4; ++ni) {
        int tok = ni * 16 + lr; if (tok > 48) tok = 48;
        qf[ni] = *(const bf16x8_t*)(base + (size_t)tok * 576 + head * 32 + g * 8);
    }

    const float* bmh = bm + (size_t)head * 4096;
    f32x4_t acc[4][4];
    #pragma unroll
    for (int mi = 0; mi < 4; ++mi)
        #pragma unroll
        for (int ni = 0; ni < 4; ++ni)
            acc[mi][ni] = *(const f32x4_t*)(bmh + ((mi * 4 + ni) * 64 + lane) * 4);
    __builtin_amdgcn_s_setprio(1);   // T5: favor MFMA wave vs other blocks' loads
    #pragma unroll
    for (int mi = 0; mi < 4; ++mi)
        #pragma unroll
        for (int ni = 0; ni < 4; ++ni)
            acc[mi][ni] = __builtin_amdgcn_mfma_f32_16x16x32_bf16(kf[mi], qf[ni], acc[mi][ni], 0, 0, 0);
    __builtin_amdgcn_s_setprio(0);

    float inv[4];
    #pragma unroll
    for (int ni = 0; ni < 4; ++ni) {
        float mx = -1e30f;
        #pragma unroll
        for (int mi = 0; mi < 3; ++mi)
            #pragma unroll
            for (int r = 0; r < 4; ++r) mx = fmaxf(mx, acc[mi][ni][r]);
        mx = fmaxf(mx, (g == 0) ? acc[3][ni][0] : -1e30f);
        mx = fmaxf(mx, __shfl_xor(mx, 16));
        mx = fmaxf(mx, __shfl_xor(mx, 32));
        float p[16], ss = 0.f;
        #pragma unroll
        for (int mi = 0; mi < 3; ++mi)
            #pragma unroll
            for (int r = 0; r < 4; ++r) {
                float e = __expf(acc[mi][ni][r] - mx);
                p[mi * 4 + r] = e; ss += e;
            }
        float e48 = (g == 0) ? __expf(acc[3][ni][0] - mx) : 0.f;
        p[12] = e48; p[13] = p[14] = p[15] = 0.f; ss += e48;
        ss += __shfl_xor(ss, 16);
        ss += __shfl_xor(ss, 32);
        inv[ni] = 1.f / ss;
        int q = ni * 16 + lr;
        #pragma unroll
        for (int mi = 0; mi < 4; ++mi) {
            *(unsigned int*)&P[q][mi * 16 + g * 4]     = pack2bf(p[mi * 4 + 0], p[mi * 4 + 1]);
            *(unsigned int*)&P[q][mi * 16 + g * 4 + 2] = pack2bf(p[mi * 4 + 2], p[mi * 4 + 3]);
        }
    }
    __syncthreads();

    f32x4_t oacc[2][4] = {};
    #pragma unroll
    for (int kt = 0; kt < 2; ++kt) {
        bf16x8_t va[2], pb[4];
        #pragma unroll
        for (int mt = 0; mt < 2; ++mt)
            va[mt] = *(const bf16x8_t*)&VT[mt * 16 + lr][kt * 32 + g * 8];
        #pragma unroll
        for (int nt = 0; nt < 4; ++nt)
            pb[nt] = *(const bf16x8_t*)&P[nt * 16 + lr][kt * 32 + g * 8];
        __builtin_amdgcn_s_setprio(1);
        #pragma unroll
        for (int mt = 0; mt < 2; ++mt)
            #pragma unroll
            for (int nt = 0; nt < 4; ++nt)
                oacc[mt][nt] = __builtin_amdgcn_mfma_f32_16x16x32_bf16(va[mt], pb[nt], oacc[mt][nt], 0, 0, 0);
        __builtin_amdgcn_s_setprio(0);
    }

    #pragma unroll
    for (int nt = 0; nt < 4; ++nt) {
        int q = nt * 16 + lr;
        if (q < 49) {
            size_t tokg = (size_t)(win0 + wloc) * 49 + q;
            unsigned short* op = outp + tokg * 192 + head * 32;
            #pragma unroll
            for (int mt = 0; mt < 2; ++mt) {
                int d0 = mt * 16 + g * 4;
                float a0 = oacc[mt][nt][0] * inv[nt], a1 = oacc[mt][nt][1] * inv[nt];
                float a2 = oacc[mt][nt][2] * inv[nt], a3 = oacc[mt][nt][3] * inv[nt];
                *(unsigned int*)(op + d0)     = pack2bf(a0, a1);
                *(unsigned int*)(op + d0 + 2) = pack2bf(a2, a3);
            }
        }
    }
}

// ---------------- host launch ----------------
extern "C" void kernel_launch(void* const* d_in, const int* in_sizes, int n_in,
                              void* d_out, int out_size, void* d_ws, size_t ws_size,
                              hipStream_t stream) {
    (void)in_sizes; (void)n_in; (void)out_size; (void)ws_size;
    const float* X     = (const float*)d_in[0];
    const float* ln1_g = (const float*)d_in[1];
    const float* ln1_b = (const float*)d_in[2];
    const float* ln2_g = (const float*)d_in[3];
    const float* ln2_b = (const float*)d_in[4];
    const float* qkv_w[2]  = { (const float*)d_in[5],  (const float*)d_in[10] };
    const float* qkv_b[2]  = { (const float*)d_in[6],  (const float*)d_in[11] };
    const float* proj_w[2] = { (const float*)d_in[7],  (const float*)d_in[12] };
    const float* proj_b[2] = { (const float*)d_in[8],  (const float*)d_in[13] };
    const float* btab[2]   = { (const float*)d_in[9],  (const float*)d_in[14] };
    const float* w1 = (const float*)d_in[15];
    const float* b1 = (const float*)d_in[16];
    const float* w2 = (const float*)d_in[17];
    const float* b2 = (const float*)d_in[18];

    char* p = (char*)d_ws;
    auto takeb = [&](size_t bytes) -> char* {
        char* r = p;
        p += (bytes + 255) & ~(size_t)255;
        return r;
    };
    auto take = [&](size_t elems) -> unsigned short* {
        return (unsigned short*)takeb(elems * 2);
    };
    unsigned short* WTq[2]; unsigned short* WTp[2];
    WTq[0] = take(576 * 192); WTp[0] = take(192 * 192);
    WTq[1] = take(576 * 192); WTp[1] = take(192 * 192);
    unsigned short* WT1 = take(768 * 192);
    unsigned short* WT2 = take(192 * 768);
    float* biasM = (float*)takeb(2 * 24576 * sizeof(float));
    unsigned short* B0 = take((size_t)NTOK * 192);            // ln1 out -> attn out -> ln2 out (fused)
    unsigned short* B1 = take((size_t)TOK_PER_CHUNK * 768);   // qkv chunk / mlp hidden chunk
    unsigned short* TK = take((size_t)NTOK * 192);            // bf16 trunk (block-1 frame, LINEAR)

    wt_all_kernel<<<dim3(576, 6), dim3(256), 0, stream>>>(
        qkv_w[0], qkv_w[1], proj_w[0], proj_w[1], w1, w2,
        WTq[0], WTq[1], WTp[0], WTp[1], WT1, WT2);
    bias_kernel<<<dim3(96, 2), dim3(256), 0, stream>>>(btab[0], btab[1], biasM);

    for (int blk = 0; blk < 2; ++blk) {
        // LN1: blk0 reads f32 input X (linear); blk1 reads bf16 trunk (roll-read)
        if (blk == 0)
            ln_kernel<0, 0><<<dim3(NTOK / 8), dim3(256), 0, stream>>>((const void*)X, B0, ln1_g, ln1_b);
        else
            ln_kernel<1, 1><<<dim3(NTOK / 8), dim3(256), 0, stream>>>((const void*)TK, B0, ln1_g, ln1_b);

        for (int c = 0; c < NCHUNK; ++c) {
            int row0 = c * TOK_PER_CHUNK;
            gemm_kernel<576, 192, 6, EP_QKV><<<dim3((TOK_PER_CHUNK / 128) * 6), dim3(256), 0, stream>>>(
                B0 + (size_t)row0 * 192, WTq[blk], qkv_b[blk], nullptr, (void*)B1, row0);
            attn_kernel<<<dim3(6, WIN_PER_CHUNK), dim3(64), 0, stream>>>(
                B1, biasM + (size_t)blk * 24576, B0, c * WIN_PER_CHUNK);
        }

        // Fused PROJ + residual + LN2: A=B0 (attn out), writes post-LN2 B0 in place.
        // Residual: blk0 = X (f32, linear), blk1 = TK (bf16, roll-read).
        if (blk == 0)
            projln_kernel<0><<<dim3(NTOK / 128), dim3(256), 0, stream>>>(
                B0, WTp[blk], proj_b[blk], (const void*)X, ln2_g, ln2_b, B0);
        else
            projln_kernel<1><<<dim3(NTOK / 128), dim3(256), 0, stream>>>(
                B0, WTp[blk], proj_b[blk], (const void*)TK, ln2_g, ln2_b, B0);

        for (int c = 0; c < NCHUNK; ++c) {
            int row0 = c * TOK_PER_CHUNK;
            gemm_kernel<768, 192, 8, EP_MLP1><<<dim3((TOK_PER_CHUNK / 128) * 8), dim3(256), 0, stream>>>(
                B0 + (size_t)row0 * 192, WT1, b1, nullptr, (void*)B1, row0);
            if (blk == 0)
                gemm_kernel<192, 768, 2, EP_MLP2_TRUNK><<<dim3((TOK_PER_CHUNK / 128) * 2), dim3(256), 0, stream>>>(
                    B1, WT2, b2, (const void*)(B0 + (size_t)row0 * 192), (void*)TK, row0);
            else
                gemm_kernel<192, 768, 2, EP_MLP2_OUT><<<dim3((TOK_PER_CHUNK / 128) * 2), dim3(256), 0, stream>>>(
                    B1, WT2, b2, (const void*)(B0 + (size_t)row0 * 192), (void*)d_out, row0);
        }
    }
}